// Round 1
// baseline (428.430 us; speedup 1.0000x reference)
//
#include <hip/hip_runtime.h>

// Problem dims (fixed by the reference): B=256, T=100, D=1024, H=128, C=5
constexpr int Bsz = 256;
constexpr int Tn  = 100;
constexpr int Dn  = 1024;
constexpr int Hn  = 128;
constexpr int Cn  = 5;

// float64 values of np.exp(-1/10), np.exp(-1/20)
#define D1 0.9048374180359595731642491
#define D2 0.9512294245007140090914253

typedef double double4_t __attribute__((ext_vector_type(4)));

// ---------------------------------------------------------------------------
// W1 f32 -> f64 into workspace (1024*128 = 131072 elements)
// ---------------------------------------------------------------------------
__global__ __launch_bounds__(256) void cvt_w1(const float* __restrict__ W1,
                                              double* __restrict__ W1d)
{
  const int i = (blockIdx.x * 256 + threadIdx.x) * 4;
  float4 v = *(const float4*)(W1 + i);
  double2 a, b;
  a.x = (double)v.x; a.y = (double)v.y;
  b.x = (double)v.z; b.y = (double)v.w;
  *(double2*)(W1d + i)     = a;
  *(double2*)(W1d + i + 2) = b;
}

// ---------------------------------------------------------------------------
// Phase 1 (MFMA f64): Hc[r,128] += X[rows, kq*256:+256] @ W1d[slice]
//
// R8 changes (vs 403.7us baseline at MfmaUtil=58%, Occupancy=39%):
//  * LDS was 33792B -> 4 blocks/CU resident; grid=1600 (6.25/CU) ran as TWO
//    block-waves (1024+576) -> dispatch quantization was the dominant stall.
//    SC 128->64 with As[2][32][4][20] f32 = 20480B -> 7 blocks/CU -> all 1600
//    blocks co-resident in ONE wave. __launch_bounds__(256,7) caps VGPR.
//  * A re-laid out as [m][kq][g] (g=k0/4): lane's 4 consecutive k-steps come
//    from ONE ds_read_b128 (8 reads/sub-chunk vs 32 scalar b32), and the
//    (4m+5kq+g) mod 8 16B-group pattern is bank-conflict-free (old APAD=33
//    layout was a 4-way conflict on every read: SQ_LDS_BANK_CONFLICT=3.28M).
//  * Structure otherwise identical: double-buffer + register prefetch, one
//    barrier per sub-chunk, TILE_M=32, KSPL=4, atomic-add epilogue onto
//    memset-zeroed Hc, self-calibrating D-layout probe.
// ---------------------------------------------------------------------------
constexpr int TILE_M = 32;
constexpr int KSPL   = 4;
constexpr int KH     = Dn / KSPL;     // 256 k per block
constexpr int SC     = 64;            // staging sub-chunk (k)
constexpr int NS     = KH / SC;       // 4
constexpr int GPAD   = 20;            // 16 g-groups + 4 pad (f32)

__global__ __launch_bounds__(256, 7) void gemm_mfma_f64(
    const float* __restrict__ X, const double* __restrict__ W1d,
    double* __restrict__ Hc, int t0, int Tc)
{
  // As[buf][m][kq][g] : element (m, k) at [m][k&3][k>>2].  20480 B total.
  __shared__ __align__(16) float As[2][TILE_M][4][GPAD];

  const int tid   = threadIdx.x;
  const int mt    = blockIdx.x >> 2;
  const int kspl  = blockIdx.x & 3;
  const int m0    = mt * TILE_M;
  const int kbase = kspl * KH;

  // staging: thread t -> A row rA=t>>3 (0..31), float4 k-group c8=t&7 (+ j*8)
  const int rA = tid >> 3;
  const int c8 = tid & 7;
  const int rc   = m0 + rA;
  const int bidx = rc / Tc;
  const int tl   = rc - bidx * Tc;
  const int grow = bidx * Tn + t0 + tl;
  const float* Apt = X + (size_t)grow * Dn + kbase;

  // compute: wave w -> n-tiles {w*16, w*16+64}, m-subtiles {0,16}
  const int w    = tid >> 6;
  const int lane = tid & 63;
  const int mA   = lane & 15;         // A row / B col index supplied
  const int kq   = lane >> 4;         // k index supplied (0..3)
  const int n0   = w * 16;

  // --- D-layout probe: D[i][j] = 16*i + j ------------------------------
  int drow[4], dcol[4];
  {
    const double ap  = (kq == 0) ? (double)(16 * mA) : (kq == 1 ? 1.0 : 0.0);
    const double bpv = (kq == 0) ? 1.0 : (kq == 1 ? (double)mA : 0.0);
    double4_t pz = {0.0, 0.0, 0.0, 0.0};
    pz = __builtin_amdgcn_mfma_f64_16x16x4f64(ap, bpv, pz, 0, 0, 0);
    #pragma unroll
    for (int r = 0; r < 4; ++r) {
      const int p = (int)pz[r];
      drow[r] = p >> 4;
      dcol[r] = p & 15;
    }
  }

  double4_t acc00 = {0.0, 0.0, 0.0, 0.0};  // m-sub 0, n-tile 0
  double4_t acc01 = {0.0, 0.0, 0.0, 0.0};  // m-sub 0, n-tile 1
  double4_t acc10 = {0.0, 0.0, 0.0, 0.0};  // m-sub 1, n-tile 0
  double4_t acc11 = {0.0, 0.0, 0.0, 0.0};  // m-sub 1, n-tile 1

  // prefetch sub-chunk 0: 2 float4 per thread (32 m x 64 k / 256 thr)
  float4 pf[2];
  #pragma unroll
  for (int j = 0; j < 2; ++j)
    pf[j] = *(const float4*)(Apt + 4 * (c8 + j * 8));

  int buf = 0;
  for (int s = 0; s < NS; ++s) {
    // write staged registers into LDS buffer `buf` ([m][kq][g] layout):
    // float4 covers k = 4*g .. 4*g+3  ->  kq planes 0..3 at group g
    #pragma unroll
    for (int j = 0; j < 2; ++j) {
      const int g = c8 + j * 8;
      As[buf][rA][0][g] = pf[j].x;
      As[buf][rA][1][g] = pf[j].y;
      As[buf][rA][2][g] = pf[j].z;
      As[buf][rA][3][g] = pf[j].w;
    }
    __syncthreads();

    // prefetch sub-chunk s+1 (overlaps compute below)
    if (s + 1 < NS) {
      #pragma unroll
      for (int j = 0; j < 2; ++j)
        pf[j] = *(const float4*)(Apt + (s + 1) * SC + 4 * (c8 + j * 8));
    }

    const double* bp  = W1d + (size_t)(kbase + s * SC + kq) * Hn + n0 + mA;
    const float*  a0p = &As[buf][mA][kq][0];
    const float*  a1p = &As[buf][16 + mA][kq][0];

    #pragma unroll
    for (int gb = 0; gb < 4; ++gb) {
      // one b128 read supplies this lane's a-values for 4 k0-steps
      const float4 av0 = *(const float4*)(a0p + gb * 4);
      const float4 av1 = *(const float4*)(a1p + gb * 4);
      #pragma unroll
      for (int i = 0; i < 4; ++i) {
        const size_t ko = (size_t)(4 * (gb * 4 + i)) * Hn;   // k0 * Hn
        const double b0 = bp[ko];
        const double b1 = bp[ko + 64];
        const double a0 = (double)av0[i];
        const double a1 = (double)av1[i];
        acc00 = __builtin_amdgcn_mfma_f64_16x16x4f64(a0, b0, acc00, 0, 0, 0);
        acc01 = __builtin_amdgcn_mfma_f64_16x16x4f64(a0, b1, acc01, 0, 0, 0);
        acc10 = __builtin_amdgcn_mfma_f64_16x16x4f64(a1, b0, acc10, 0, 0, 0);
        acc11 = __builtin_amdgcn_mfma_f64_16x16x4f64(a1, b1, acc11, 0, 0, 0);
      }
    }
    buf ^= 1;
  }

  // epilogue: atomic-add partial K-quarter into Hc (memset-zeroed base)
  #pragma unroll
  for (int r = 0; r < 4; ++r) {
    double* e00 = &Hc[(size_t)(m0 + drow[r]) * Hn + n0 + dcol[r]];
    double* e01 = &Hc[(size_t)(m0 + drow[r]) * Hn + n0 + 64 + dcol[r]];
    double* e10 = &Hc[(size_t)(m0 + 16 + drow[r]) * Hn + n0 + dcol[r]];
    double* e11 = &Hc[(size_t)(m0 + 16 + drow[r]) * Hn + n0 + 64 + dcol[r]];
    __hip_atomic_fetch_add(e00, acc00[r], __ATOMIC_RELAXED, __HIP_MEMORY_SCOPE_AGENT);
    __hip_atomic_fetch_add(e01, acc01[r], __ATOMIC_RELAXED, __HIP_MEMORY_SCOPE_AGENT);
    __hip_atomic_fetch_add(e10, acc10[r], __ATOMIC_RELAXED, __HIP_MEMORY_SCOPE_AGENT);
    __hip_atomic_fetch_add(e11, acc11[r], __ATOMIC_RELAXED, __HIP_MEMORY_SCOPE_AGENT);
  }
}

// ---------------------------------------------------------------------------
// Phase 2: per-batch-row LIF scan over t in [t0, t0+Tc), fp64 state in ws.
// One 64-lane wave per batch row; each lane owns 2 hidden neurons.
// ---------------------------------------------------------------------------
__global__ __launch_bounds__(64) void snn_scan_f64(
    const double* __restrict__ Hc, const float* __restrict__ b1,
    const float* __restrict__ W2, const float* __restrict__ b2,
    double* __restrict__ v1s, double* __restrict__ v2s,
    double* __restrict__ accs, float* __restrict__ out, int t0, int Tc)
{
#pragma clang fp contract(off)
  const int b    = blockIdx.x;
  const int lane = threadIdx.x;
  const int j0   = lane * 2;

  double w2a[Cn], w2b[Cn], bb2[Cn];
  #pragma unroll
  for (int c = 0; c < Cn; ++c) {
    w2a[c] = (double)W2[(size_t)j0 * Cn + c];
    w2b[c] = (double)W2[(size_t)(j0 + 1) * Cn + c];
    bb2[c] = (double)b2[c];
  }
  const double b1a = (double)b1[j0];
  const double b1b = (double)b1[j0 + 1];

  double v1a, v1b, v2[Cn], acc[Cn];
  if (t0 == 0) {
    v1a = 0.0; v1b = 0.0;
    #pragma unroll
    for (int c = 0; c < Cn; ++c) { v2[c] = 0.0; acc[c] = 0.0; }
  } else {
    v1a = v1s[(size_t)b * Hn + j0];
    v1b = v1s[(size_t)b * Hn + j0 + 1];
    #pragma unroll
    for (int c = 0; c < Cn; ++c) {
      v2[c]  = v2s[(size_t)b * Cn + c];
      acc[c] = accs[(size_t)b * Cn + c];
    }
  }

  const double* hp = Hc + (size_t)b * Tc * Hn + j0;
  double2 hnext = *(const double2*)hp;

  for (int t = 0; t < Tc; ++t) {
    const double2 hc = hnext;
    const int tn = (t + 1 < Tc) ? (t + 1) : t;
    hnext = *(const double2*)(hp + (size_t)tn * Hn);

    // v1 = (v1*d1 + h) + b1  (left-assoc, separate roundings)
    v1a = (v1a * D1 + hc.x) + b1a;
    v1b = (v1b * D1 + hc.y) + b1b;
    const double s1a = (v1a >= 1.0) ? 1.0 : 0.0;
    const double s1b = (v1b >= 1.0) ? 1.0 : 0.0;
    v1a = (v1a >= 1.0) ? 0.0 : v1a;
    v1b = (v1b >= 1.0) ? 0.0 : v1b;

    // p[c] = sum_j s1[j] * W2[j,c]  (fp64 butterfly)
    double p[Cn];
    #pragma unroll
    for (int c = 0; c < Cn; ++c)
      p[c] = s1a * w2a[c] + s1b * w2b[c];
    #pragma unroll
    for (int off = 32; off > 0; off >>= 1) {
      #pragma unroll
      for (int c = 0; c < Cn; ++c)
        p[c] += __shfl_xor(p[c], off);
    }

    // v2 = ((v2*d2) + p) + b2
    #pragma unroll
    for (int c = 0; c < Cn; ++c) {
      const double v = ((v2[c] * D2) + p[c]) + bb2[c];
      const double s2 = (v >= 1.0) ? 1.0 : 0.0;
      v2[c]  = (v >= 1.0) ? 0.0 : v;
      acc[c] += s2;
    }
  }

  // persist state for next chunk
  v1s[(size_t)b * Hn + j0]     = v1a;
  v1s[(size_t)b * Hn + j0 + 1] = v1b;
  if (lane == 0) {
    #pragma unroll
    for (int c = 0; c < Cn; ++c) {
      v2s[(size_t)b * Cn + c]  = v2[c];
      accs[(size_t)b * Cn + c] = acc[c];
    }
    if (t0 + Tc == Tn) {
      #pragma unroll
      for (int c = 0; c < Cn; ++c)
        out[(size_t)b * Cn + c] = (float)(acc[c] / 100.0);
    }
  }
}

// ---------------------------------------------------------------------------
extern "C" void kernel_launch(void* const* d_in, const int* in_sizes, int n_in,
                              void* d_out, int out_size, void* d_ws, size_t ws_size,
                              hipStream_t stream) {
  const float* X  = (const float*)d_in[0];   // [B,T,D]
  const float* W1 = (const float*)d_in[1];   // [D,H]
  const float* b1 = (const float*)d_in[2];   // [H]
  const float* W2 = (const float*)d_in[3];   // [H,C]
  const float* b2 = (const float*)d_in[4];   // [C]
  float* out = (float*)d_out;                // [B,C]

  // ws layout: W1d (1 MB) | Hc [B*Tc,H] | v1s | v2s | accs   (all f64)
  const size_t w1Doubles    = (size_t)Dn * Hn;                    // 131072
  const size_t stateDoubles = (size_t)Bsz * Hn + 2 * (size_t)Bsz * Cn;
  static const int cands[] = {100, 50, 25, 20, 10, 5, 4, 2, 1};
  int Tc = 1;
  for (int i = 0; i < 9; ++i) {
    const size_t need =
        (w1Doubles + (size_t)Bsz * cands[i] * Hn + stateDoubles) * sizeof(double);
    if (need <= ws_size) { Tc = cands[i]; break; }
  }

  double* W1d  = (double*)d_ws;
  double* Hc   = W1d + w1Doubles;                    // [B*Tc, H]
  double* v1s  = Hc  + (size_t)Bsz * Tc * Hn;        // [B, H]
  double* v2s  = v1s + (size_t)Bsz * Hn;             // [B, C]
  double* accs = v2s + (size_t)Bsz * Cn;             // [B, C]
  const size_t hcBytes = (size_t)Bsz * Tc * Hn * sizeof(double);

  cvt_w1<<<dim3((Dn * Hn) / (256 * 4)), dim3(256), 0, stream>>>(W1, W1d);

  for (int t0 = 0; t0 < Tn; t0 += Tc) {
    const int rows = Bsz * Tc;
    hipMemsetAsync(Hc, 0, hcBytes, stream);          // atomic accumulation base
    gemm_mfma_f64<<<dim3((rows / TILE_M) * KSPL), dim3(256), 0, stream>>>(
        X, W1d, Hc, t0, Tc);
    snn_scan_f64<<<dim3(Bsz), dim3(64), 0, stream>>>(Hc, b1, W2, b2,
                                                     v1s, v2s, accs, out, t0, Tc);
  }
}

// Round 3
// 385.896 us; speedup vs baseline: 1.1102x; 1.1102x over previous
//
#include <hip/hip_runtime.h>

// Problem dims (fixed by the reference): B=256, T=100, D=1024, H=128, C=5
constexpr int Bsz = 256;
constexpr int Tn  = 100;
constexpr int Dn  = 1024;
constexpr int Hn  = 128;
constexpr int Cn  = 5;

// float64 values of np.exp(-1/10), np.exp(-1/20)
#define D1 0.9048374180359595731642491
#define D2 0.9512294245007140090914253

typedef double double4_t __attribute__((ext_vector_type(4)));

// ---------------------------------------------------------------------------
// W1 f32 -> f64 into workspace (1024*128 = 131072 elements)
// ---------------------------------------------------------------------------
__global__ __launch_bounds__(256) void cvt_w1(const float* __restrict__ W1,
                                              double* __restrict__ W1d)
{
  const int i = (blockIdx.x * 256 + threadIdx.x) * 4;
  float4 v = *(const float4*)(W1 + i);
  double2 a, b;
  a.x = (double)v.x; a.y = (double)v.y;
  b.x = (double)v.z; b.y = (double)v.w;
  *(double2*)(W1d + i)     = a;
  *(double2*)(W1d + i + 2) = b;
}

// ---------------------------------------------------------------------------
// Phase 1 (MFMA f64): Hc[r,128] += X[rows, kq*256:+256] @ W1d[slice]
//
// R10 == R9 resubmitted verbatim: R9's bench was an infra failure
// ("container failed twice"), never evaluated. Kernel re-audited for
// OOB/hang: none. Theory under test (vs 403.7us R7 baseline at
// MfmaUtil=58%, SQ_LDS_BANK_CONFLICT=3.28M):
//  * LDS layout [m][k], KPAD=132 (33792B, 4 blocks/CU):
//    - reads: bank=(4*mA+kq+k0)%32, 4mA+kq covers 0..63 once -> uniform
//      2-way (free), vs R7's 4-way conflict.
//    - staging: one ds_write_b128 per float4 (4 vs 16 scalar writes),
//      start-bank 4*((rA+c8)%8) uniform -> zero excess conflict.
//  * Rolling B-register prefetch (k0+4's b0/b1 loaded before k0's MFMAs,
//    last iter peeled): load-to-use distance = one MFMA batch (~500cy).
// R8 lesson kept: do NOT raise blocks/CU past 4 (Hc atomic lines thrash
// L2 -> HBM traffic doubles), do NOT cap VGPR with min-waves bound.
// Arithmetic order unchanged -> absmax stays 0.
// ---------------------------------------------------------------------------
constexpr int TILE_M = 32;
constexpr int KSPL   = 4;
constexpr int KH     = Dn / KSPL;     // 256 k per block
constexpr int SC     = 128;           // staging sub-chunk (k)
constexpr int NS     = KH / SC;       // 2
constexpr int KPAD   = 132;           // 128 k + 4 pad (f32)

__global__ __launch_bounds__(256) void gemm_mfma_f64(
    const float* __restrict__ X, const double* __restrict__ W1d,
    double* __restrict__ Hc, int t0, int Tc)
{
  // As[buf][m][k] : 2 * 32 * 132 * 4 = 33792 B
  __shared__ __align__(16) float As[2][TILE_M][KPAD];

  const int tid   = threadIdx.x;
  const int mt    = blockIdx.x >> 2;
  const int kspl  = blockIdx.x & 3;
  const int m0    = mt * TILE_M;
  const int kbase = kspl * KH;

  // staging: thread t -> A row rA=t>>3 (0..31), float4 k-group c8=t&7 (+ j*8)
  const int rA = tid >> 3;
  const int c8 = tid & 7;
  const int rc   = m0 + rA;
  const int bidx = rc / Tc;
  const int tl   = rc - bidx * Tc;
  const int grow = bidx * Tn + t0 + tl;
  const float* Apt = X + (size_t)grow * Dn + kbase;

  // compute: wave w -> n-tiles {w*16, w*16+64}, m-subtiles {0,16}
  const int w    = tid >> 6;
  const int lane = tid & 63;
  const int mA   = lane & 15;         // A row / B col index supplied
  const int kq   = lane >> 4;         // k index supplied (0..3)
  const int n0   = w * 16;

  // --- D-layout probe: D[i][j] = 16*i + j ------------------------------
  int drow[4], dcol[4];
  {
    const double ap  = (kq == 0) ? (double)(16 * mA) : (kq == 1 ? 1.0 : 0.0);
    const double bpv = (kq == 0) ? 1.0 : (kq == 1 ? (double)mA : 0.0);
    double4_t pz = {0.0, 0.0, 0.0, 0.0};
    pz = __builtin_amdgcn_mfma_f64_16x16x4f64(ap, bpv, pz, 0, 0, 0);
    #pragma unroll
    for (int r = 0; r < 4; ++r) {
      const int p = (int)pz[r];
      drow[r] = p >> 4;
      dcol[r] = p & 15;
    }
  }

  double4_t acc00 = {0.0, 0.0, 0.0, 0.0};  // m-sub 0, n-tile 0
  double4_t acc01 = {0.0, 0.0, 0.0, 0.0};  // m-sub 0, n-tile 1
  double4_t acc10 = {0.0, 0.0, 0.0, 0.0};  // m-sub 1, n-tile 0
  double4_t acc11 = {0.0, 0.0, 0.0, 0.0};  // m-sub 1, n-tile 1

  // prefetch sub-chunk 0: 4 float4 per thread (32 m x 128 k / 256 thr)
  float4 pf[4];
  #pragma unroll
  for (int j = 0; j < 4; ++j)
    pf[j] = *(const float4*)(Apt + 4 * (c8 + j * 8));

  int buf = 0;
  for (int s = 0; s < NS; ++s) {
    // write staged registers into LDS buffer `buf` ([m][k] layout):
    // one ds_write_b128 per float4, conflict-free start-bank pattern
    #pragma unroll
    for (int j = 0; j < 4; ++j)
      *(float4*)&As[buf][rA][4 * (c8 + j * 8)] = pf[j];
    __syncthreads();

    // prefetch sub-chunk s+1 (overlaps compute below)
    if (s + 1 < NS) {
      #pragma unroll
      for (int j = 0; j < 4; ++j)
        pf[j] = *(const float4*)(Apt + (s + 1) * SC + 4 * (c8 + j * 8));
    }

    const double* bp = W1d + (size_t)(kbase + s * SC + kq) * Hn + n0 + mA;
    double b0 = bp[0];
    double b1 = bp[64];

    #pragma unroll 4
    for (int k0 = 0; k0 < SC - 4; k0 += 4) {
      const double nb0 = bp[(size_t)(k0 + 4) * Hn];        // next n-tile 0
      const double nb1 = bp[(size_t)(k0 + 4) * Hn + 64];   // next n-tile 1
      const double a0  = (double)As[buf][mA][k0 + kq];     // m-sub 0
      const double a1  = (double)As[buf][16 + mA][k0 + kq];// m-sub 1
      acc00 = __builtin_amdgcn_mfma_f64_16x16x4f64(a0, b0, acc00, 0, 0, 0);
      acc01 = __builtin_amdgcn_mfma_f64_16x16x4f64(a0, b1, acc01, 0, 0, 0);
      acc10 = __builtin_amdgcn_mfma_f64_16x16x4f64(a1, b0, acc10, 0, 0, 0);
      acc11 = __builtin_amdgcn_mfma_f64_16x16x4f64(a1, b1, acc11, 0, 0, 0);
      b0 = nb0; b1 = nb1;
    }
    { // peeled last k-step (k0 = SC-4), b already in registers
      const double a0 = (double)As[buf][mA][SC - 4 + kq];
      const double a1 = (double)As[buf][16 + mA][SC - 4 + kq];
      acc00 = __builtin_amdgcn_mfma_f64_16x16x4f64(a0, b0, acc00, 0, 0, 0);
      acc01 = __builtin_amdgcn_mfma_f64_16x16x4f64(a0, b1, acc01, 0, 0, 0);
      acc10 = __builtin_amdgcn_mfma_f64_16x16x4f64(a1, b0, acc10, 0, 0, 0);
      acc11 = __builtin_amdgcn_mfma_f64_16x16x4f64(a1, b1, acc11, 0, 0, 0);
    }
    buf ^= 1;
  }

  // epilogue: atomic-add partial K-quarter into Hc (memset-zeroed base)
  #pragma unroll
  for (int r = 0; r < 4; ++r) {
    double* e00 = &Hc[(size_t)(m0 + drow[r]) * Hn + n0 + dcol[r]];
    double* e01 = &Hc[(size_t)(m0 + drow[r]) * Hn + n0 + 64 + dcol[r]];
    double* e10 = &Hc[(size_t)(m0 + 16 + drow[r]) * Hn + n0 + dcol[r]];
    double* e11 = &Hc[(size_t)(m0 + 16 + drow[r]) * Hn + n0 + 64 + dcol[r]];
    __hip_atomic_fetch_add(e00, acc00[r], __ATOMIC_RELAXED, __HIP_MEMORY_SCOPE_AGENT);
    __hip_atomic_fetch_add(e01, acc01[r], __ATOMIC_RELAXED, __HIP_MEMORY_SCOPE_AGENT);
    __hip_atomic_fetch_add(e10, acc10[r], __ATOMIC_RELAXED, __HIP_MEMORY_SCOPE_AGENT);
    __hip_atomic_fetch_add(e11, acc11[r], __ATOMIC_RELAXED, __HIP_MEMORY_SCOPE_AGENT);
  }
}

// ---------------------------------------------------------------------------
// Phase 2: per-batch-row LIF scan over t in [t0, t0+Tc), fp64 state in ws.
// One 64-lane wave per batch row; each lane owns 2 hidden neurons.
// ---------------------------------------------------------------------------
__global__ __launch_bounds__(64) void snn_scan_f64(
    const double* __restrict__ Hc, const float* __restrict__ b1,
    const float* __restrict__ W2, const float* __restrict__ b2,
    double* __restrict__ v1s, double* __restrict__ v2s,
    double* __restrict__ accs, float* __restrict__ out, int t0, int Tc)
{
#pragma clang fp contract(off)
  const int b    = blockIdx.x;
  const int lane = threadIdx.x;
  const int j0   = lane * 2;

  double w2a[Cn], w2b[Cn], bb2[Cn];
  #pragma unroll
  for (int c = 0; c < Cn; ++c) {
    w2a[c] = (double)W2[(size_t)j0 * Cn + c];
    w2b[c] = (double)W2[(size_t)(j0 + 1) * Cn + c];
    bb2[c] = (double)b2[c];
  }
  const double b1a = (double)b1[j0];
  const double b1b = (double)b1[j0 + 1];

  double v1a, v1b, v2[Cn], acc[Cn];
  if (t0 == 0) {
    v1a = 0.0; v1b = 0.0;
    #pragma unroll
    for (int c = 0; c < Cn; ++c) { v2[c] = 0.0; acc[c] = 0.0; }
  } else {
    v1a = v1s[(size_t)b * Hn + j0];
    v1b = v1s[(size_t)b * Hn + j0 + 1];
    #pragma unroll
    for (int c = 0; c < Cn; ++c) {
      v2[c]  = v2s[(size_t)b * Cn + c];
      acc[c] = accs[(size_t)b * Cn + c];
    }
  }

  const double* hp = Hc + (size_t)b * Tc * Hn + j0;
  double2 hnext = *(const double2*)hp;

  for (int t = 0; t < Tc; ++t) {
    const double2 hc = hnext;
    const int tn = (t + 1 < Tc) ? (t + 1) : t;
    hnext = *(const double2*)(hp + (size_t)tn * Hn);

    // v1 = (v1*d1 + h) + b1  (left-assoc, separate roundings)
    v1a = (v1a * D1 + hc.x) + b1a;
    v1b = (v1b * D1 + hc.y) + b1b;
    const double s1a = (v1a >= 1.0) ? 1.0 : 0.0;
    const double s1b = (v1b >= 1.0) ? 1.0 : 0.0;
    v1a = (v1a >= 1.0) ? 0.0 : v1a;
    v1b = (v1b >= 1.0) ? 0.0 : v1b;

    // p[c] = sum_j s1[j] * W2[j,c]  (fp64 butterfly)
    double p[Cn];
    #pragma unroll
    for (int c = 0; c < Cn; ++c)
      p[c] = s1a * w2a[c] + s1b * w2b[c];
    #pragma unroll
    for (int off = 32; off > 0; off >>= 1) {
      #pragma unroll
      for (int c = 0; c < Cn; ++c)
        p[c] += __shfl_xor(p[c], off);
    }

    // v2 = ((v2*d2) + p) + b2
    #pragma unroll
    for (int c = 0; c < Cn; ++c) {
      const double v = ((v2[c] * D2) + p[c]) + bb2[c];
      const double s2 = (v >= 1.0) ? 1.0 : 0.0;
      v2[c]  = (v >= 1.0) ? 0.0 : v;
      acc[c] += s2;
    }
  }

  // persist state for next chunk
  v1s[(size_t)b * Hn + j0]     = v1a;
  v1s[(size_t)b * Hn + j0 + 1] = v1b;
  if (lane == 0) {
    #pragma unroll
    for (int c = 0; c < Cn; ++c) {
      v2s[(size_t)b * Cn + c]  = v2[c];
      accs[(size_t)b * Cn + c] = acc[c];
    }
    if (t0 + Tc == Tn) {
      #pragma unroll
      for (int c = 0; c < Cn; ++c)
        out[(size_t)b * Cn + c] = (float)(acc[c] / 100.0);
    }
  }
}

// ---------------------------------------------------------------------------
extern "C" void kernel_launch(void* const* d_in, const int* in_sizes, int n_in,
                              void* d_out, int out_size, void* d_ws, size_t ws_size,
                              hipStream_t stream) {
  const float* X  = (const float*)d_in[0];   // [B,T,D]
  const float* W1 = (const float*)d_in[1];   // [D,H]
  const float* b1 = (const float*)d_in[2];   // [H]
  const float* W2 = (const float*)d_in[3];   // [H,C]
  const float* b2 = (const float*)d_in[4];   // [C]
  float* out = (float*)d_out;                // [B,C]

  // ws layout: W1d (1 MB) | Hc [B*Tc,H] | v1s | v2s | accs   (all f64)
  const size_t w1Doubles    = (size_t)Dn * Hn;                    // 131072
  const size_t stateDoubles = (size_t)Bsz * Hn + 2 * (size_t)Bsz * Cn;
  static const int cands[] = {100, 50, 25, 20, 10, 5, 4, 2, 1};
  int Tc = 1;
  for (int i = 0; i < 9; ++i) {
    const size_t need =
        (w1Doubles + (size_t)Bsz * cands[i] * Hn + stateDoubles) * sizeof(double);
    if (need <= ws_size) { Tc = cands[i]; break; }
  }

  double* W1d  = (double*)d_ws;
  double* Hc   = W1d + w1Doubles;                    // [B*Tc, H]
  double* v1s  = Hc  + (size_t)Bsz * Tc * Hn;        // [B, H]
  double* v2s  = v1s + (size_t)Bsz * Hn;             // [B, C]
  double* accs = v2s + (size_t)Bsz * Cn;             // [B, C]
  const size_t hcBytes = (size_t)Bsz * Tc * Hn * sizeof(double);

  cvt_w1<<<dim3((Dn * Hn) / (256 * 4)), dim3(256), 0, stream>>>(W1, W1d);

  for (int t0 = 0; t0 < Tn; t0 += Tc) {
    const int rows = Bsz * Tc;
    hipMemsetAsync(Hc, 0, hcBytes, stream);          // atomic accumulation base
    gemm_mfma_f64<<<dim3((rows / TILE_M) * KSPL), dim3(256), 0, stream>>>(
        X, W1d, Hc, t0, Tc);
    snn_scan_f64<<<dim3(Bsz), dim3(64), 0, stream>>>(Hc, b1, W2, b2,
                                                     v1s, v2s, accs, out, t0, Tc);
  }
}

// Round 4
// 309.635 us; speedup vs baseline: 1.3837x; 1.2463x over previous
//
#include <hip/hip_runtime.h>

// Problem dims (fixed by the reference): B=256, T=100, D=1024, H=128, C=5
constexpr int Bsz = 256;
constexpr int Tn  = 100;
constexpr int Dn  = 1024;
constexpr int Hn  = 128;
constexpr int Cn  = 5;

// float64 values of np.exp(-1/10), np.exp(-1/20)
#define D1 0.9048374180359595731642491
#define D2 0.9512294245007140090914253

typedef double double4_t __attribute__((ext_vector_type(4)));

// ---------------------------------------------------------------------------
// W1 f32 -> f64 into workspace (1024*128 = 131072 elements)
// ---------------------------------------------------------------------------
__global__ __launch_bounds__(256) void cvt_w1(const float* __restrict__ W1,
                                              double* __restrict__ W1d)
{
  const int i = (blockIdx.x * 256 + threadIdx.x) * 4;
  float4 v = *(const float4*)(W1 + i);
  double2 a, b;
  a.x = (double)v.x; a.y = (double)v.y;
  b.x = (double)v.z; b.y = (double)v.w;
  *(double2*)(W1d + i)     = a;
  *(double2*)(W1d + i + 2) = b;
}

// ---------------------------------------------------------------------------
// Phase 1 (MFMA f64) — UNCHANGED from R10 (proven ~50us/dispatch, ~85% of
// f64-MFMA peak): [m][k] KPAD=132 LDS (uniform 2-way-free banks), b128
// staging writes, rolling B-register prefetch, 4 blocks/CU, KSPL=4 atomics.
// ---------------------------------------------------------------------------
constexpr int TILE_M = 32;
constexpr int KSPL   = 4;
constexpr int KH     = Dn / KSPL;     // 256 k per block
constexpr int SC     = 128;           // staging sub-chunk (k)
constexpr int NS     = KH / SC;       // 2
constexpr int KPAD   = 132;           // 128 k + 4 pad (f32)

__global__ __launch_bounds__(256) void gemm_mfma_f64(
    const float* __restrict__ X, const double* __restrict__ W1d,
    double* __restrict__ Hc, int t0, int Tc)
{
  // As[buf][m][k] : 2 * 32 * 132 * 4 = 33792 B
  __shared__ __align__(16) float As[2][TILE_M][KPAD];

  const int tid   = threadIdx.x;
  const int mt    = blockIdx.x >> 2;
  const int kspl  = blockIdx.x & 3;
  const int m0    = mt * TILE_M;
  const int kbase = kspl * KH;

  // staging: thread t -> A row rA=t>>3 (0..31), float4 k-group c8=t&7 (+ j*8)
  const int rA = tid >> 3;
  const int c8 = tid & 7;
  const int rc   = m0 + rA;
  const int bidx = rc / Tc;
  const int tl   = rc - bidx * Tc;
  const int grow = bidx * Tn + t0 + tl;
  const float* Apt = X + (size_t)grow * Dn + kbase;

  // compute: wave w -> n-tiles {w*16, w*16+64}, m-subtiles {0,16}
  const int w    = tid >> 6;
  const int lane = tid & 63;
  const int mA   = lane & 15;         // A row / B col index supplied
  const int kq   = lane >> 4;         // k index supplied (0..3)
  const int n0   = w * 16;

  // --- D-layout probe: D[i][j] = 16*i + j ------------------------------
  int drow[4], dcol[4];
  {
    const double ap  = (kq == 0) ? (double)(16 * mA) : (kq == 1 ? 1.0 : 0.0);
    const double bpv = (kq == 0) ? 1.0 : (kq == 1 ? (double)mA : 0.0);
    double4_t pz = {0.0, 0.0, 0.0, 0.0};
    pz = __builtin_amdgcn_mfma_f64_16x16x4f64(ap, bpv, pz, 0, 0, 0);
    #pragma unroll
    for (int r = 0; r < 4; ++r) {
      const int p = (int)pz[r];
      drow[r] = p >> 4;
      dcol[r] = p & 15;
    }
  }

  double4_t acc00 = {0.0, 0.0, 0.0, 0.0};  // m-sub 0, n-tile 0
  double4_t acc01 = {0.0, 0.0, 0.0, 0.0};  // m-sub 0, n-tile 1
  double4_t acc10 = {0.0, 0.0, 0.0, 0.0};  // m-sub 1, n-tile 0
  double4_t acc11 = {0.0, 0.0, 0.0, 0.0};  // m-sub 1, n-tile 1

  // prefetch sub-chunk 0: 4 float4 per thread (32 m x 128 k / 256 thr)
  float4 pf[4];
  #pragma unroll
  for (int j = 0; j < 4; ++j)
    pf[j] = *(const float4*)(Apt + 4 * (c8 + j * 8));

  int buf = 0;
  for (int s = 0; s < NS; ++s) {
    // write staged registers into LDS buffer `buf` ([m][k] layout):
    // one ds_write_b128 per float4, conflict-free start-bank pattern
    #pragma unroll
    for (int j = 0; j < 4; ++j)
      *(float4*)&As[buf][rA][4 * (c8 + j * 8)] = pf[j];
    __syncthreads();

    // prefetch sub-chunk s+1 (overlaps compute below)
    if (s + 1 < NS) {
      #pragma unroll
      for (int j = 0; j < 4; ++j)
        pf[j] = *(const float4*)(Apt + (s + 1) * SC + 4 * (c8 + j * 8));
    }

    const double* bp = W1d + (size_t)(kbase + s * SC + kq) * Hn + n0 + mA;
    double b0 = bp[0];
    double b1 = bp[64];

    #pragma unroll 4
    for (int k0 = 0; k0 < SC - 4; k0 += 4) {
      const double nb0 = bp[(size_t)(k0 + 4) * Hn];        // next n-tile 0
      const double nb1 = bp[(size_t)(k0 + 4) * Hn + 64];   // next n-tile 1
      const double a0  = (double)As[buf][mA][k0 + kq];     // m-sub 0
      const double a1  = (double)As[buf][16 + mA][k0 + kq];// m-sub 1
      acc00 = __builtin_amdgcn_mfma_f64_16x16x4f64(a0, b0, acc00, 0, 0, 0);
      acc01 = __builtin_amdgcn_mfma_f64_16x16x4f64(a0, b1, acc01, 0, 0, 0);
      acc10 = __builtin_amdgcn_mfma_f64_16x16x4f64(a1, b0, acc10, 0, 0, 0);
      acc11 = __builtin_amdgcn_mfma_f64_16x16x4f64(a1, b1, acc11, 0, 0, 0);
      b0 = nb0; b1 = nb1;
    }
    { // peeled last k-step (k0 = SC-4), b already in registers
      const double a0 = (double)As[buf][mA][SC - 4 + kq];
      const double a1 = (double)As[buf][16 + mA][SC - 4 + kq];
      acc00 = __builtin_amdgcn_mfma_f64_16x16x4f64(a0, b0, acc00, 0, 0, 0);
      acc01 = __builtin_amdgcn_mfma_f64_16x16x4f64(a0, b1, acc01, 0, 0, 0);
      acc10 = __builtin_amdgcn_mfma_f64_16x16x4f64(a1, b0, acc10, 0, 0, 0);
      acc11 = __builtin_amdgcn_mfma_f64_16x16x4f64(a1, b1, acc11, 0, 0, 0);
    }
    buf ^= 1;
  }

  // epilogue: atomic-add partial K-quarter into Hc (memset-zeroed base)
  #pragma unroll
  for (int r = 0; r < 4; ++r) {
    double* e00 = &Hc[(size_t)(m0 + drow[r]) * Hn + n0 + dcol[r]];
    double* e01 = &Hc[(size_t)(m0 + drow[r]) * Hn + n0 + 64 + dcol[r]];
    double* e10 = &Hc[(size_t)(m0 + 16 + drow[r]) * Hn + n0 + dcol[r]];
    double* e11 = &Hc[(size_t)(m0 + 16 + drow[r]) * Hn + n0 + 64 + dcol[r]];
    __hip_atomic_fetch_add(e00, acc00[r], __ATOMIC_RELAXED, __HIP_MEMORY_SCOPE_AGENT);
    __hip_atomic_fetch_add(e01, acc01[r], __ATOMIC_RELAXED, __HIP_MEMORY_SCOPE_AGENT);
    __hip_atomic_fetch_add(e10, acc10[r], __ATOMIC_RELAXED, __HIP_MEMORY_SCOPE_AGENT);
    __hip_atomic_fetch_add(e11, acc11[r], __ATOMIC_RELAXED, __HIP_MEMORY_SCOPE_AGENT);
  }
}

// ---------------------------------------------------------------------------
// Phase 2 scan, v2 (R11). Old scan: 137us/dispatch, 1 wave/CU, latency-bound
// on 6-stage x 5-class f64 shuffle butterfly per timestep (60 ds_bpermute in
// 6 dependent ~120cy waits, zero latency hiding at Occupancy=2.8%).
// Rework exploits: (a) spikes are BINARY -> __ballot gives the full 128-
// neuron spike vector as 2 scalar u64/step (no f64 reduction in the serial
// chain); (b) output = spike_count/100 exactly -> p summation order is free
// (f64 1e-16 reorder can't flip spikes; GEMM atomics already reorder sums
// run-to-run and absmax stays 0).
// Structure (256 thr = 4 waves, 1 block per batch row):
//  P0: stage Hc slice (Tc*128 f64, <=51.2KB) + W2 (f64, 5.1KB) into LDS.
//  P1: wave 0 runs v1 chain: FMA+cmp+2 ballots/step, LDS 1-ahead prefetch.
//  P2: all Tc*5 (t,c) dot-products in parallel, one per thread: 128-term
//      masked sum over LDS W2 (cndmask+add, no branches).
//  P3: threads 0..4 run independent per-class v2/acc chains from LDS Pp.
// LDS total 59.1KB < 64KB static limit (Tc capped at 50 host-side).
// ---------------------------------------------------------------------------
constexpr int TCMAX = 50;

__global__ __launch_bounds__(256) void snn_scan_v2(
    const double* __restrict__ Hc, const float* __restrict__ b1,
    const float* __restrict__ W2, const float* __restrict__ b2,
    double* __restrict__ v1s, double* __restrict__ v2s,
    double* __restrict__ accs, float* __restrict__ out, int t0, int Tc)
{
#pragma clang fp contract(off)
  __shared__ __align__(16) double HcL[TCMAX * Hn];        // 51200 B
  __shared__ double W2d[Hn * Cn];                          // 5120 B
  __shared__ double Pp[TCMAX * Cn];                        // 2000 B
  __shared__ unsigned long long Mk[TCMAX][2];              // 800 B

  const int b   = blockIdx.x;
  const int tid = threadIdx.x;

  // ---- P0: stage W2 (f32->f64) and the Hc row-slice into LDS -------------
  for (int i = tid; i < Hn * Cn; i += 256)
    W2d[i] = (double)W2[i];
  {
    const double* src = Hc + (size_t)b * Tc * Hn;
    const int nd2 = Tc * (Hn / 2);            // double2 elements
    int i = tid;
    for (; i + 3 * 256 < nd2; i += 4 * 256) { // 4-deep load pipeline
      double2 a0 = *(const double2*)(src + 2 * (i + 0 * 256));
      double2 a1 = *(const double2*)(src + 2 * (i + 1 * 256));
      double2 a2 = *(const double2*)(src + 2 * (i + 2 * 256));
      double2 a3 = *(const double2*)(src + 2 * (i + 3 * 256));
      *(double2*)&HcL[2 * (i + 0 * 256)] = a0;
      *(double2*)&HcL[2 * (i + 1 * 256)] = a1;
      *(double2*)&HcL[2 * (i + 2 * 256)] = a2;
      *(double2*)&HcL[2 * (i + 3 * 256)] = a3;
    }
    for (; i < nd2; i += 256)
      *(double2*)&HcL[2 * i] = *(const double2*)(src + 2 * i);
  }
  __syncthreads();

  // ---- P1: wave 0 runs the layer-1 LIF chain, emitting spike masks -------
  if (tid < 64) {
    const int lane = tid;
    const int j0   = lane * 2;
    const double b1a = (double)b1[j0];
    const double b1b = (double)b1[j0 + 1];

    double v1a, v1b;
    if (t0 == 0) { v1a = 0.0; v1b = 0.0; }
    else {
      v1a = v1s[(size_t)b * Hn + j0];
      v1b = v1s[(size_t)b * Hn + j0 + 1];
    }

    double2 hnext = *(const double2*)&HcL[j0];         // t = 0
    for (int t = 0; t < Tc; ++t) {
      const double2 hc = hnext;
      const int tn = (t + 1 < Tc) ? (t + 1) : t;
      hnext = *(const double2*)&HcL[tn * Hn + j0];     // 1-ahead prefetch

      // v1 = (v1*d1 + h) + b1  (left-assoc, separate roundings — unchanged)
      v1a = (v1a * D1 + hc.x) + b1a;
      v1b = (v1b * D1 + hc.y) + b1b;
      const bool ca = (v1a >= 1.0);
      const bool cb = (v1b >= 1.0);
      const unsigned long long mA = __ballot(ca);      // neuron 2L  <- bit L
      const unsigned long long mB = __ballot(cb);      // neuron 2L+1<- bit L
      if (ca) v1a = 0.0;
      if (cb) v1b = 0.0;
      if (lane == 0) { Mk[t][0] = mA; Mk[t][1] = mB; }
    }
    v1s[(size_t)b * Hn + j0]     = v1a;
    v1s[(size_t)b * Hn + j0 + 1] = v1b;
  }
  __syncthreads();

  // ---- P2: all (t,c) classifier dot-products in parallel ------------------
  // p[t][c] = sum_j spike[j,t] * W2[j,c]; spike bits from masks; summation
  // order j-ascending (exactness: integer-count output, huge spike margins).
  for (int pi = tid; pi < Tc * Cn; pi += 256) {
    const int tt = pi / Cn;
    const int cc = pi - tt * Cn;
    const unsigned long long mA = Mk[tt][0];
    const unsigned long long mB = Mk[tt][1];
    double sA = 0.0, sB = 0.0;
    #pragma unroll
    for (int L = 0; L < 64; ++L) {
      sA += ((mA >> L) & 1ull) ? W2d[(2 * L) * Cn + cc]     : 0.0;
      sB += ((mB >> L) & 1ull) ? W2d[(2 * L + 1) * Cn + cc] : 0.0;
    }
    Pp[pi] = sA + sB;
  }
  __syncthreads();

  // ---- P3: per-class v2/acc chains (5 independent threads) ----------------
  if (tid < Cn) {
    const int c = tid;
    const double bb2 = (double)b2[c];
    double v2, acc;
    if (t0 == 0) { v2 = 0.0; acc = 0.0; }
    else {
      v2  = v2s[(size_t)b * Cn + c];
      acc = accs[(size_t)b * Cn + c];
    }
    double pn = Pp[c];                                  // t = 0
    for (int t = 0; t < Tc; ++t) {
      const double p = pn;
      const int tn = (t + 1 < Tc) ? (t + 1) : t;
      pn = Pp[tn * Cn + c];                             // 1-ahead prefetch
      const double v = ((v2 * D2) + p) + bb2;           // unchanged order
      const bool s2 = (v >= 1.0);
      v2 = s2 ? 0.0 : v;
      acc += s2 ? 1.0 : 0.0;
    }
    v2s[(size_t)b * Cn + c]  = v2;
    accs[(size_t)b * Cn + c] = acc;
    if (t0 + Tc == Tn)
      out[(size_t)b * Cn + c] = (float)(acc / 100.0);
  }
}

// ---------------------------------------------------------------------------
extern "C" void kernel_launch(void* const* d_in, const int* in_sizes, int n_in,
                              void* d_out, int out_size, void* d_ws, size_t ws_size,
                              hipStream_t stream) {
  const float* X  = (const float*)d_in[0];   // [B,T,D]
  const float* W1 = (const float*)d_in[1];   // [D,H]
  const float* b1 = (const float*)d_in[2];   // [H]
  const float* W2 = (const float*)d_in[3];   // [H,C]
  const float* b2 = (const float*)d_in[4];   // [C]
  float* out = (float*)d_out;                // [B,C]

  // ws layout: W1d (1 MB) | Hc [B*Tc,H] | v1s | v2s | accs   (all f64)
  // Tc capped at TCMAX=50 so the scan's LDS staging fits 64KB static.
  const size_t w1Doubles    = (size_t)Dn * Hn;                    // 131072
  const size_t stateDoubles = (size_t)Bsz * Hn + 2 * (size_t)Bsz * Cn;
  static const int cands[] = {50, 25, 20, 10, 5, 4, 2, 1};
  int Tc = 1;
  for (int i = 0; i < 8; ++i) {
    const size_t need =
        (w1Doubles + (size_t)Bsz * cands[i] * Hn + stateDoubles) * sizeof(double);
    if (need <= ws_size) { Tc = cands[i]; break; }
  }

  double* W1d  = (double*)d_ws;
  double* Hc   = W1d + w1Doubles;                    // [B*Tc, H]
  double* v1s  = Hc  + (size_t)Bsz * Tc * Hn;        // [B, H]
  double* v2s  = v1s + (size_t)Bsz * Hn;             // [B, C]
  double* accs = v2s + (size_t)Bsz * Cn;             // [B, C]
  const size_t hcBytes = (size_t)Bsz * Tc * Hn * sizeof(double);

  cvt_w1<<<dim3((Dn * Hn) / (256 * 4)), dim3(256), 0, stream>>>(W1, W1d);

  for (int t0 = 0; t0 < Tn; t0 += Tc) {
    const int rows = Bsz * Tc;
    hipMemsetAsync(Hc, 0, hcBytes, stream);          // atomic accumulation base
    gemm_mfma_f64<<<dim3((rows / TILE_M) * KSPL), dim3(256), 0, stream>>>(
        X, W1d, Hc, t0, Tc);
    snn_scan_v2<<<dim3(Bsz), dim3(256), 0, stream>>>(Hc, b1, W2, b2,
                                                     v1s, v2s, accs, out, t0, Tc);
  }
}